// Round 7
// baseline (173.031 us; speedup 1.0000x reference)
//
#include <hip/hip_runtime.h>
#include <hip/hip_bf16.h>
#include <math.h>

#define Bn 8
#define Ln 512
#define Dn 768
#define NHn 12
#define DHn 64
#define K1n 20
#define K2n 20

// workspace layout (bytes)
#define WS_ACC    0          // double acc[8]: [0]=pair_num [1]=trip_num [2]=trip_cnt; bytes 48..51 = done-counter
#define WS_GSCORE 64         // float g_score[8*512]
#define WS_LOCR   16448      // float loc_rows[8*20*512] (320 KB)
#define WS_GTOP   344128     // int g_top[8*20]
#define WS_SBF    357568     // ushort sbf[8*12*512*64] bf16 head-major
#define WS_TBF    6649024    // ushort tbf[...] (ends 12940480)
#define WS_ZERO_BYTES 344128 // acc + counter + g_score + loc_rows

typedef __attribute__((ext_vector_type(8))) short bf16x8;
typedef __attribute__((ext_vector_type(4))) float f32x4;

__device__ inline unsigned short f2bf(float x) {
  __hip_bfloat16 h = __float2bfloat16(x);
  return *reinterpret_cast<unsigned short*>(&h);
}
__device__ inline float bf2f(unsigned short u) {
  return __uint_as_float(((unsigned int)u) << 16);
}

// ---------------------------------------------------------------------------
// Prep: fp32 [b][row][h*64+k] -> bf16 head-major [b][h][row][k]
// ---------------------------------------------------------------------------
__global__ __launch_bounds__(256) void prep_bf16_kernel(
    const float* __restrict__ s, const float* __restrict__ t,
    unsigned short* __restrict__ sbf, unsigned short* __restrict__ tbf) {
  int gid = blockIdx.x * 256 + threadIdx.x;
  int f = gid * 4;
  int col = f % Dn;
  int rb = f / Dn;
  int row = rb & (Ln - 1);
  int b = rb >> 9;
  int h = col >> 6;
  int k = col & 63;
  size_t dst = (((size_t)(b * NHn + h) * Ln + row) * DHn + k);
  float4 vs = *(const float4*)(s + f);
  float4 vt = *(const float4*)(t + f);
  ushort4 us, ut;
  us.x = f2bf(vs.x); us.y = f2bf(vs.y); us.z = f2bf(vs.z); us.w = f2bf(vs.w);
  ut.x = f2bf(vt.x); ut.y = f2bf(vt.y); ut.z = f2bf(vt.z); ut.w = f2bf(vt.w);
  *(ushort4*)(sbf + dst) = us;
  *(ushort4*)(tbf + dst) = ut;
}

// ---------------------------------------------------------------------------
// Kernel A (two-pass recompute, column-split): one block per (b, h, 32-row
// tile). Wave (wr,wc) owns 16 rows x 256 cols -> grid 1536 = 6 blocks/CU
// (~75% occupancy vs round 6's 3 blocks/CU). Row sums via one 2-way LDS
// exchange. Pass 2 recomputes t-scores+exp (bf16 MFMA deterministic).
// ---------------------------------------------------------------------------
__global__ __launch_bounds__(256) void pairA_kernel(
    const unsigned short* __restrict__ sbf, const unsigned short* __restrict__ tbf,
    const float* __restrict__ mask, float* __restrict__ g_score,
    double* __restrict__ acc) {
  const int b = blockIdx.x & 7;
  const int r = blockIdx.x >> 3;          // 0..191
  const int it = r / NHn;                 // 0..15
  const int h = r - it * NHn;             // 0..11
  const int tid = threadIdx.x;
  const int w = tid >> 6;
  const int wr = w >> 1;                  // row strip 0/1
  const int wc = w & 1;                   // col half 0/1
  const int lane = tid & 63;
  const int lr = lane & 15, lg = lane >> 4;

  __shared__ float Mcol[Ln];
  __shared__ float gcol[Ln];
  __shared__ float redsum[2][2][16];      // [wc][wr][row]
  __shared__ float wred[4];

  for (int j = tid; j < Ln; j += 256) {
    Mcol[j] = mask[b * Ln + j];
    gcol[j] = 0.0f;
  }
  __syncthreads();

  const size_t hb = (size_t)(b * NHn + h) * Ln;
  const int rw = it * 32 + wr * 16;
  const unsigned short* pas = sbf + (hb + rw + lr) * DHn + lg * 8;
  const unsigned short* pat = tbf + (hb + rw + lr) * DHn + lg * 8;
  bf16x8 sa0 = *(const bf16x8*)pas;
  bf16x8 sa1 = *(const bf16x8*)(pas + 32);
  bf16x8 ta0 = *(const bf16x8*)pat;
  bf16x8 ta1 = *(const bf16x8*)(pat + 32);
  float mrow[4];
  #pragma unroll
  for (int q = 0; q < 4; ++q) mrow[q] = Mcol[rw + lg * 4 + q];

  const f32x4 zero4 = {0.0f, 0.0f, 0.0f, 0.0f};
  const int cbase = wc * 256;
  float lpair = 0.0f;
  float rsum[4] = {0.0f, 0.0f, 0.0f, 0.0f};

  // ---- pass 1: diff^2 + unnormalized row sums over this wave's 256 cols ----
  for (int ct = 0; ct < 16; ++ct) {
    const int j0 = cbase + ct * 16;
    const unsigned short* pbs = sbf + (hb + j0 + lr) * DHn + lg * 8;
    const unsigned short* pbt = tbf + (hb + j0 + lr) * DHn + lg * 8;
    bf16x8 sb0 = *(const bf16x8*)pbs;
    bf16x8 sb1 = *(const bf16x8*)(pbs + 32);
    bf16x8 tb0 = *(const bf16x8*)pbt;
    bf16x8 tb1 = *(const bf16x8*)(pbt + 32);
    f32x4 sacc = __builtin_amdgcn_mfma_f32_16x16x32_bf16(sa0, sb0, zero4, 0, 0, 0);
    sacc = __builtin_amdgcn_mfma_f32_16x16x32_bf16(sa1, sb1, sacc, 0, 0, 0);
    f32x4 tacc = __builtin_amdgcn_mfma_f32_16x16x32_bf16(ta0, tb0, zero4, 0, 0, 0);
    tacc = __builtin_amdgcn_mfma_f32_16x16x32_bf16(ta1, tb1, tacc, 0, 0, 0);
    const float mj = Mcol[j0 + lr];
    #pragma unroll
    for (int q = 0; q < 4; ++q) {
      const float mm = mrow[q] * mj;
      const float ss = sacc[q] * 0.125f * mm;
      const float st = tacc[q] * 0.125f * mm;
      const float d = ss - st;
      lpair += d * d;
      rsum[q] += __expf(st + (1.0f - mm) * (-10000.0f));
    }
  }

  // wave-local partial row sums -> LDS exchange across col halves
  #pragma unroll
  for (int o = 1; o < 16; o <<= 1) {
    #pragma unroll
    for (int q = 0; q < 4; ++q) rsum[q] += __shfl_xor(rsum[q], o, 64);
  }
  if (lr == 0) {
    #pragma unroll
    for (int q = 0; q < 4; ++q) redsum[wc][wr][lg * 4 + q] = rsum[q];
  }
  __syncthreads();
  float rscale[4];
  #pragma unroll
  for (int q = 0; q < 4; ++q) {
    const int ri = lg * 4 + q;
    rscale[q] = mrow[q] / fmaxf(redsum[0][wr][ri] + redsum[1][wr][ri], 1e-30f);
  }

  // ---- pass 2: recompute e, scale, column sums ----
  for (int ct = 0; ct < 16; ++ct) {
    const int j0 = cbase + ct * 16;
    const unsigned short* pbt = tbf + (hb + j0 + lr) * DHn + lg * 8;
    bf16x8 tb0 = *(const bf16x8*)pbt;
    bf16x8 tb1 = *(const bf16x8*)(pbt + 32);
    f32x4 tacc = __builtin_amdgcn_mfma_f32_16x16x32_bf16(ta0, tb0, zero4, 0, 0, 0);
    tacc = __builtin_amdgcn_mfma_f32_16x16x32_bf16(ta1, tb1, tacc, 0, 0, 0);
    const float mj = Mcol[j0 + lr];
    float pc = 0.0f;
    #pragma unroll
    for (int q = 0; q < 4; ++q) {
      const float mm = mrow[q] * mj;
      const float st = tacc[q] * 0.125f * mm;
      const float e = __expf(st + (1.0f - mm) * (-10000.0f));
      pc += e * rscale[q];
    }
    pc += __shfl_xor(pc, 16, 64);
    pc += __shfl_xor(pc, 32, 64);
    if (lg == 0) atomicAdd(&gcol[j0 + lr], pc);
  }

  // pair-loss partial
  #pragma unroll
  for (int o = 1; o < 64; o <<= 1) lpair += __shfl_xor(lpair, o, 64);
  if (lane == 0) wred[w] = lpair;
  __syncthreads();

  if (tid == 0) {
    atomicAdd(&acc[0], (double)((wred[0] + wred[1]) + (wred[2] + wred[3])));
  }
  {
    const int j0 = tid, j1 = tid + 256;
    atomicAdd(&g_score[b * Ln + j0], gcol[j0] * Mcol[j0]);
    atomicAdd(&g_score[b * Ln + j1], gcol[j1] * Mcol[j1]);
  }
}

// ---------------------------------------------------------------------------
// Kernel B (+ inline topk_g): one block per (b, h) = 96 blocks. Wave 0
// recomputes the g_score top-k (deterministic, identical across the 12 h
// blocks of a batch); h==0 block also publishes g_top for the triplet kernel.
// Then recompute att rows for those 20 rows, accumulate over h into loc_rows.
// ---------------------------------------------------------------------------
__global__ __launch_bounds__(256, 4) void pairB_kernel(
    const unsigned short* __restrict__ tbf, const float* __restrict__ mask,
    const float* __restrict__ g_score, int* __restrict__ g_top,
    float* __restrict__ loc_rows) {
  const int b = blockIdx.x & 7;
  const int h = blockIdx.x >> 3;
  const int tid = threadIdx.x;
  const int w = tid >> 6, lane = tid & 63;
  const int lr = lane & 15, lg = lane >> 4;
  const int cw = w * 128;

  __shared__ int gidx[32];
  __shared__ float mrow_s[32];
  __shared__ float rscale_s[32];
  __shared__ float redsum[4][32];
  __shared__ float McolB[Ln];
  __shared__ unsigned short es[32][Ln + 8];

  for (int j = tid; j < Ln; j += 256) McolB[j] = mask[b * Ln + j];
  if (w == 1 && lane < 32 - K1n) gidx[K1n + lane] = 0;
  if (w == 0) {
    // single-wave register top-k over g_score[b] (tie -> lowest index)
    float v[8];
    #pragma unroll
    for (int q = 0; q < 8; ++q) v[q] = g_score[b * Ln + q * 64 + lane];
    for (int r = 0; r < K1n; ++r) {
      float bv = v[0]; int bq = 0;
      #pragma unroll
      for (int q = 1; q < 8; ++q) if (v[q] > bv) { bv = v[q]; bq = q; }
      int bj = bq * 64 + lane;
      #pragma unroll
      for (int o = 1; o < 64; o <<= 1) {
        float ov = __shfl_xor(bv, o, 64);
        int oj = __shfl_xor(bj, o, 64);
        if (ov > bv || (ov == bv && oj < bj)) { bv = ov; bj = oj; }
      }
      if (lane == 0) {
        gidx[r] = bj;
        if (h == 0) g_top[b * K1n + r] = bj;
      }
      const int wq = bj >> 6, wl = bj & 63;
      #pragma unroll
      for (int q = 0; q < 8; ++q)
        if (q == wq && lane == wl) v[q] = -3.0e38f;
    }
  }
  __syncthreads();
  if (tid < 32) mrow_s[tid] = (tid < K1n) ? McolB[gidx[tid]] : 0.0f;
  __syncthreads();

  const size_t hb = (size_t)(b * NHn + h) * Ln;
  bf16x8 ta[2][2];
  #pragma unroll
  for (int rt = 0; rt < 2; ++rt) {
    const unsigned short* p = tbf + (hb + gidx[rt * 16 + lr]) * DHn + lg * 8;
    ta[rt][0] = *(const bf16x8*)p;
    ta[rt][1] = *(const bf16x8*)(p + 32);
  }
  const f32x4 zero4 = {0.0f, 0.0f, 0.0f, 0.0f};
  float rsum[2][4] = {{0, 0, 0, 0}, {0, 0, 0, 0}};
  #pragma unroll
  for (int ct = 0; ct < 8; ++ct) {
    const int j0 = cw + ct * 16;
    const unsigned short* pb = tbf + (hb + j0 + lr) * DHn + lg * 8;
    bf16x8 tb0 = *(const bf16x8*)pb;
    bf16x8 tb1 = *(const bf16x8*)(pb + 32);
    const float mj = McolB[j0 + lr];
    #pragma unroll
    for (int rt = 0; rt < 2; ++rt) {
      f32x4 tacc = __builtin_amdgcn_mfma_f32_16x16x32_bf16(ta[rt][0], tb0, zero4, 0, 0, 0);
      tacc = __builtin_amdgcn_mfma_f32_16x16x32_bf16(ta[rt][1], tb1, tacc, 0, 0, 0);
      #pragma unroll
      for (int q = 0; q < 4; ++q) {
        const int ri = rt * 16 + lg * 4 + q;
        const float mm = mrow_s[ri] * mj;
        const float st = tacc[q] * 0.125f * mm;
        const float e = __expf(st + (1.0f - mm) * (-10000.0f));
        rsum[rt][q] += e;
        es[ri][j0 + lr] = f2bf(e);
      }
    }
  }
  #pragma unroll
  for (int o = 1; o < 16; o <<= 1) {
    #pragma unroll
    for (int rt = 0; rt < 2; ++rt)
      #pragma unroll
      for (int q = 0; q < 4; ++q) rsum[rt][q] += __shfl_xor(rsum[rt][q], o, 64);
  }
  if (lr == 0) {
    #pragma unroll
    for (int rt = 0; rt < 2; ++rt)
      #pragma unroll
      for (int q = 0; q < 4; ++q) redsum[w][rt * 16 + lg * 4 + q] = rsum[rt][q];
  }
  __syncthreads();
  if (tid < 32) {
    const float fs = redsum[0][tid] + redsum[1][tid] + redsum[2][tid] + redsum[3][tid];
    rscale_s[tid] = mrow_s[tid] / fmaxf(fs, 1e-30f);
  }
  __syncthreads();
  for (int idx = tid; idx < K1n * Ln; idx += 256) {
    const int ri = idx >> 9, j = idx & (Ln - 1);
    const float e = bf2f(es[ri][j]);
    atomicAdd(&loc_rows[(size_t)(b * K1n + ri) * Ln + j], e * rscale_s[ri] * McolB[j]);
  }
}

// ---------------------------------------------------------------------------
// Triplet (+ inline topk_l, + last-block finalize). One block per (b, i1).
// Wave 0 computes the loc-row top-k; then normalized diffs -> bf16 LDS and
// 20x20 Grams via MFMA. Last-finishing block combines the losses.
// ---------------------------------------------------------------------------
#define TP (Dn + 16)

__global__ __launch_bounds__(256, 1) void triplet_kernel(
    const float* __restrict__ s_rep, const float* __restrict__ t_rep,
    const float* __restrict__ mask, const int* __restrict__ g_top,
    const float* __restrict__ loc_rows, double* __restrict__ acc,
    unsigned int* __restrict__ done_cnt, float* __restrict__ out) {
  const int blk = blockIdx.x, tid = threadIdx.x;
  const int b = blk / K1n, i1 = blk % K1n;
  const int w = tid >> 6, lane = tid & 63;
  const int lr = lane & 15, lg = lane >> 4;

  __shared__ unsigned short NS[32][TP];
  __shared__ unsigned short NT[32][TP];
  __shared__ int lidx[K2n];
  __shared__ float fl2[K2n];
  __shared__ float sred[4], cred[4];
  __shared__ int is_last;
  __shared__ float red[4];

  const int g = g_top[b * K1n + i1];
  if (w == 0) {
    // single-wave top-k of loc_rows[b][i1] with diagonal zeroed
    const float* r0 = loc_rows + (size_t)(b * K1n + i1) * Ln;
    float v[8];
    #pragma unroll
    for (int q = 0; q < 8; ++q) {
      const int j = q * 64 + lane;
      v[q] = (j == g) ? 0.0f : r0[j];
    }
    for (int r = 0; r < K2n; ++r) {
      float bv = v[0]; int bq = 0;
      #pragma unroll
      for (int q = 1; q < 8; ++q) if (v[q] > bv) { bv = v[q]; bq = q; }
      int bj = bq * 64 + lane;
      #pragma unroll
      for (int o = 1; o < 64; o <<= 1) {
        float ov = __shfl_xor(bv, o, 64);
        int oj = __shfl_xor(bj, o, 64);
        if (ov > bv || (ov == bv && oj < bj)) { bv = ov; bj = oj; }
      }
      if (lane == 0) lidx[r] = bj;
      const int wq = bj >> 6, wl = bj & 63;
      #pragma unroll
      for (int q = 0; q < 8; ++q)
        if (q == wq && lane == wl) v[q] = -3.0e38f;
    }
  }
  __syncthreads();
  if (tid < K2n)
    fl2[tid] = (mask[b * Ln + g] + mask[b * Ln + lidx[tid]] == 2.0f) ? 1.0f : 0.0f;
  __syncthreads();

  const float* pgs = s_rep + (size_t)(b * Ln + g) * Dn;
  const float* pgt = t_rep + (size_t)(b * Ln + g) * Dn;
  for (int j = w; j < K2n; j += 4) {
    const float* pls = s_rep + (size_t)(b * Ln + lidx[j]) * Dn;
    const float* plt = t_rep + (size_t)(b * Ln + lidx[j]) * Dn;
    float4 ds[3], dt[3];
    float ssq = 0.0f, tsq = 0.0f;
    #pragma unroll
    for (int q = 0; q < 3; ++q) {
      const int c = lane * 4 + q * 256;
      float4 a = *(const float4*)&pgs[c];
      float4 x = *(const float4*)&pls[c];
      ds[q] = make_float4(a.x - x.x, a.y - x.y, a.z - x.z, a.w - x.w);
      ssq += ds[q].x * ds[q].x + ds[q].y * ds[q].y + ds[q].z * ds[q].z + ds[q].w * ds[q].w;
      float4 c2 = *(const float4*)&pgt[c];
      float4 y = *(const float4*)&plt[c];
      dt[q] = make_float4(c2.x - y.x, c2.y - y.y, c2.z - y.z, c2.w - y.w);
      tsq += dt[q].x * dt[q].x + dt[q].y * dt[q].y + dt[q].z * dt[q].z + dt[q].w * dt[q].w;
    }
    #pragma unroll
    for (int o = 1; o < 64; o <<= 1) {
      ssq += __shfl_xor(ssq, o, 64);
      tsq += __shfl_xor(tsq, o, 64);
    }
    const float sinv = 1.0f / fmaxf(sqrtf(ssq), 1e-12f);
    const float tinv = 1.0f / fmaxf(sqrtf(tsq), 1e-12f);
    #pragma unroll
    for (int q = 0; q < 3; ++q) {
      const int c = lane * 4 + q * 256;
      ushort4 us, ut;
      us.x = f2bf(ds[q].x * sinv); us.y = f2bf(ds[q].y * sinv);
      us.z = f2bf(ds[q].z * sinv); us.w = f2bf(ds[q].w * sinv);
      ut.x = f2bf(dt[q].x * tinv); ut.y = f2bf(dt[q].y * tinv);
      ut.z = f2bf(dt[q].z * tinv); ut.w = f2bf(dt[q].w * tinv);
      *(ushort4*)&NS[j][c] = us;
      *(ushort4*)&NT[j][c] = ut;
    }
  }
  __syncthreads();

  // Gram quadrant per wave: rows qr*16.., cols qc*16..
  const int qr = w >> 1, qc = w & 1;
  f32x4 sacc = {0.0f, 0.0f, 0.0f, 0.0f};
  f32x4 tacc = {0.0f, 0.0f, 0.0f, 0.0f};
  #pragma unroll
  for (int ks = 0; ks < 24; ++ks) {
    const int kk = ks * 32 + lg * 8;
    bf16x8 as = *(const bf16x8*)&NS[qr * 16 + lr][kk];
    bf16x8 bs = *(const bf16x8*)&NS[qc * 16 + lr][kk];
    bf16x8 at = *(const bf16x8*)&NT[qr * 16 + lr][kk];
    bf16x8 bt = *(const bf16x8*)&NT[qc * 16 + lr][kk];
    sacc = __builtin_amdgcn_mfma_f32_16x16x32_bf16(as, bs, sacc, 0, 0, 0);
    tacc = __builtin_amdgcn_mfma_f32_16x16x32_bf16(at, bt, tacc, 0, 0, 0);
  }
  float psum = 0.0f, pcnt = 0.0f;
  #pragma unroll
  for (int q = 0; q < 4; ++q) {
    const int j2 = qr * 16 + lg * 4 + q;    // Gram row
    const int k2 = qc * 16 + lr;            // Gram col
    if (j2 < K2n && k2 < K2n && j2 != k2) {
      const float am = fl2[j2] * fl2[k2];
      const bool smv = (am != 0.0f) && (sacc[q] != 0.0f);
      const bool tmv = (am != 0.0f) && (tacc[q] != 0.0f);
      const float sv = smv ? sacc[q] : 0.0f;
      const float tv = tmv ? tacc[q] : 0.0f;
      const float d = sv - tv;
      const float ad = fabsf(d);
      psum += (ad < 1.0f) ? 0.5f * d * d : (ad - 0.5f);
      pcnt += smv ? 1.0f : 0.0f;
    }
  }
  #pragma unroll
  for (int o = 1; o < 64; o <<= 1) {
    psum += __shfl_xor(psum, o, 64);
    pcnt += __shfl_xor(pcnt, o, 64);
  }
  if (lane == 0) { sred[w] = psum; cred[w] = pcnt; }
  __syncthreads();
  if (tid == 0) {
    atomicAdd(&acc[1], (double)(sred[0] + sred[1] + sred[2] + sred[3]));
    atomicAdd(&acc[2], (double)(cred[0] + cred[1] + cred[2] + cred[3]));
    __threadfence();
    const unsigned int done = atomicAdd(done_cnt, 1u);
    is_last = (done == (unsigned int)(Bn * K1n - 1)) ? 1 : 0;
  }
  __syncthreads();

  // last-finishing block: finalize (all acc atomics from other blocks are
  // visible: each block fenced before its counter increment)
  if (is_last) {
    double sm = 0.0;
    for (int bb = 0; bb < Bn; ++bb) {
      float p = 0.0f;
      for (int i = tid; i < Ln; i += 256) p += mask[bb * Ln + i];
      #pragma unroll
      for (int o = 1; o < 64; o <<= 1) p += __shfl_xor(p, o, 64);
      __syncthreads();
      if ((tid & 63) == 0) red[tid >> 6] = p;
      __syncthreads();
      if (tid == 0) {
        float rs = red[0] + red[1] + red[2] + red[3];
        sm += (double)rs * (double)rs;
      }
    }
    __syncthreads();
    if (tid == 0) {
      const double a0 = atomicAdd(&acc[0], 0.0);   // device-coherent reads
      const double a1 = atomicAdd(&acc[1], 0.0);
      const double a2 = atomicAdd(&acc[2], 0.0);
      const double lp = a0 / ((double)NHn * sm);
      const double lt = a1 / a2;
      out[0] = (float)(lp + lt);
    }
  }
}

// ---------------------------------------------------------------------------
extern "C" void kernel_launch(void* const* d_in, const int* in_sizes, int n_in,
                              void* d_out, int out_size, void* d_ws, size_t ws_size,
                              hipStream_t stream) {
  const float* s_rep = (const float*)d_in[0];
  const float* t_rep = (const float*)d_in[1];
  const float* mask  = (const float*)d_in[2];
  float* out = (float*)d_out;

  char* w = (char*)d_ws;
  double* acc      = (double*)(w + WS_ACC);
  unsigned int* done_cnt = (unsigned int*)(w + WS_ACC + 48);
  float* g_score   = (float*)(w + WS_GSCORE);
  float* loc_rows  = (float*)(w + WS_LOCR);
  int* g_top       = (int*)(w + WS_GTOP);
  unsigned short* sbf = (unsigned short*)(w + WS_SBF);
  unsigned short* tbf = (unsigned short*)(w + WS_TBF);

  hipMemsetAsync(d_ws, 0, WS_ZERO_BYTES, stream);

  prep_bf16_kernel<<<Bn * Ln * Dn / 4 / 256, 256, 0, stream>>>(s_rep, t_rep, sbf, tbf);
  pairA_kernel<<<Bn * NHn * (Ln / 32), 256, 0, stream>>>(sbf, tbf, mask, g_score, acc);
  pairB_kernel<<<Bn * NHn, 256, 0, stream>>>(tbf, mask, g_score, g_top, loc_rows);
  triplet_kernel<<<Bn * K1n, 256, 0, stream>>>(s_rep, t_rep, mask, g_top, loc_rows,
                                               acc, done_cnt, out);
}